// Round 9
// baseline (760.354 us; speedup 1.0000x reference)
//
#include <hip/hip_runtime.h>

#define N_NODES 100000
#define N_EDGES 1600000
#define D 64
#define H 128
#define SCAN_BS 512
#define SCAN_NBLK ((N_NODES + SCAN_BS - 1) / SCAN_BS)   // 196

// bucket pipeline
#define NB 1563              // buckets of 64 nodes: 1563*64 = 100032 >= 100000
#define NCHUNK 256
#define EPC (N_EDGES / NCHUNK)   // 6250 exactly

#define MFMA_GRID 512
#define SH_STRIDE 132

typedef __attribute__((ext_vector_type(8))) short short8;
typedef __attribute__((ext_vector_type(4))) float floatx4;
typedef __attribute__((ext_vector_type(4))) unsigned short ushort4_t;

__device__ __forceinline__ unsigned short f2bf(float f) {
    unsigned u = __builtin_bit_cast(unsigned, f);
    u += 0x7FFFu + ((u >> 16) & 1u);
    return (unsigned short)(u >> 16);
}
__device__ __forceinline__ float bf2f(unsigned short u) {
    unsigned v = ((unsigned)u) << 16;
    return __builtin_bit_cast(float, v);
}

// ===========================================================================
// utility
// ===========================================================================
__global__ __launch_bounds__(256) void k_zero(int* __restrict__ p, int n) {
    int i = blockIdx.x * 256 + threadIdx.x;
    if (i < n) p[i] = 0;
}

__global__ __launch_bounds__(256) void k_xbf16(const float4* __restrict__ x4,
                                               ushort4_t* __restrict__ y, int n4) {
    int i = blockIdx.x * 256 + threadIdx.x;
    if (i >= n4) return;
    float4 v = x4[i];
    ushort4_t o;
    o[0] = f2bf(v.x); o[1] = f2bf(v.y); o[2] = f2bf(v.z); o[3] = f2bf(v.w);
    y[i] = o;
}

// ===========================================================================
// P1: per-chunk bucket histogram in LDS -> M2[chunk][bucket] (coalesced write)
// ===========================================================================
__global__ __launch_bounds__(256) void k_bhist(const int* __restrict__ dst,
                                               int* __restrict__ M2) {
    __shared__ int hist[NB];
    int t = threadIdx.x, c = blockIdx.x;
    for (int i = t; i < NB; i += 256) hist[i] = 0;
    __syncthreads();
    const int* dp = dst + c * EPC;
    for (int i = t; i < EPC; i += 256) atomicAdd(&hist[dp[i] >> 6], 1);
    __syncthreads();
    int* mp = M2 + c * NB;
    for (int i = t; i < NB; i += 256) mp[i] = hist[i];
}

// ===========================================================================
// S1: for each bucket b, exclusive scan of M2[c][b] over c=0..255 (in place),
// and colsum[b] = total. One 64-lane wave per bucket, 16 buckets per block
// (so the strided write-back lines M2[c][b0..b0+15] are block-exclusive).
// ===========================================================================
__global__ __launch_bounds__(1024) void k_rowscan(int* __restrict__ M2,
                                                  int* __restrict__ colsum) {
    int b = blockIdx.x * 16 + (threadIdx.x >> 6);
    if (b >= NB) return;
    int l = threadIdx.x & 63;
    int c0 = l * 4;
    int v0 = M2[(c0 + 0) * NB + b];
    int v1 = M2[(c0 + 1) * NB + b];
    int v2 = M2[(c0 + 2) * NB + b];
    int v3 = M2[(c0 + 3) * NB + b];
    int tot = v0 + v1 + v2 + v3;
    int s = tot;
    for (int off = 1; off < 64; off <<= 1) {
        int u = __shfl_up(s, off, 64);
        if (l >= off) s += u;
    }
    int excl = s - tot;
    M2[(c0 + 0) * NB + b] = excl;
    M2[(c0 + 1) * NB + b] = excl + v0;
    M2[(c0 + 2) * NB + b] = excl + v0 + v1;
    M2[(c0 + 3) * NB + b] = excl + v0 + v1 + v2;
    if (l == 63) colsum[b] = s;
}

// ===========================================================================
// parametric inclusive scan (3 phases) — used for colsum (n=NB) and fallback
// ===========================================================================
__global__ __launch_bounds__(SCAN_BS) void k_scan1(const int* __restrict__ cnt,
                                                   int* __restrict__ ends,
                                                   int* __restrict__ bsum, int n) {
    __shared__ int s[SCAN_BS];
    int t = threadIdx.x, b = blockIdx.x;
    int id = b * SCAN_BS + t;
    s[t] = (id < n) ? cnt[id] : 0;
    __syncthreads();
    for (int off = 1; off < SCAN_BS; off <<= 1) {
        int u = (t >= off) ? s[t - off] : 0;
        __syncthreads();
        s[t] += u;
        __syncthreads();
    }
    if (id < n) ends[id] = s[t];
    if (t == SCAN_BS - 1) bsum[b] = s[t];
}

__global__ __launch_bounds__(256) void k_scan2(int* __restrict__ bsum, int nb) {
    __shared__ int s[256];
    int t = threadIdx.x;
    s[t] = (t < nb) ? bsum[t] : 0;
    __syncthreads();
    for (int off = 1; off < 256; off <<= 1) {
        int u = (t >= off) ? s[t - off] : 0;
        __syncthreads();
        s[t] += u;
        __syncthreads();
    }
    if (t < nb) bsum[t] = s[t];
}

__global__ __launch_bounds__(SCAN_BS) void k_scan3(int* __restrict__ ends,
                                                   const int* __restrict__ bsum, int n) {
    int t = threadIdx.x, b = blockIdx.x;
    int id = b * SCAN_BS + t;
    if (b > 0 && id < n) ends[id] += bsum[b - 1];
}

// ===========================================================================
// P3: partition edges into bucket-ordered ebuf, packed (dlow<<17)|src.
// LDS cursor atomics (no device atomics); slice-exclusive writes per block.
// ===========================================================================
__global__ __launch_bounds__(256) void k_part(const int* __restrict__ src,
                                              const int* __restrict__ dst,
                                              const int* __restrict__ M2,
                                              const int* __restrict__ bends,
                                              int* __restrict__ ebuf) {
    __shared__ int cur[NB];
    int t = threadIdx.x, c = blockIdx.x;
    const int* mp = M2 + c * NB;
    for (int i = t; i < NB; i += 256)
        cur[i] = ((i > 0) ? bends[i - 1] : 0) + mp[i];
    __syncthreads();
    const int* sp = src + c * EPC;
    const int* dp = dst + c * EPC;
    for (int i = t; i < EPC; i += 256) {
        int d = dp[i], s = sp[i];
        int p = atomicAdd(&cur[d >> 6], 1);
        ebuf[p] = s | ((d & 63) << 17);
    }
}

// ===========================================================================
// P4: one block per bucket. acc[64][64] fp32 in LDS; half-wave per edge with
// 4 edges in flight; ds_add_f32 accumulation; coalesced +x epilogue.
// ===========================================================================
__global__ __launch_bounds__(256) void k_bagg(const float* __restrict__ x,
                                              const unsigned short* __restrict__ x16,
                                              const int* __restrict__ ebuf,
                                              const int* __restrict__ bends,
                                              float* __restrict__ out) {
    __shared__ float acc[64][64];     // 16 KB
    int t = threadIdx.x, b = blockIdx.x;
    for (int i = t; i < 1024; i += 256) ((float4*)acc)[i] = make_float4(0.f, 0.f, 0.f, 0.f);
    __syncthreads();

    int estart = (b > 0) ? bends[b - 1] : 0;
    int ne = bends[b] - estart;
    const int* ep = ebuf + estart;
    int hw = t >> 5;          // half-wave 0..7
    int fp = t & 31;          // feature pair

    for (int j = hw * 4; j < ne; j += 32) {
        int n0 = (j + 0 < ne) ? ep[j + 0] : -1;
        int n1 = (j + 1 < ne) ? ep[j + 1] : -1;
        int n2 = (j + 2 < ne) ? ep[j + 2] : -1;
        int n3 = (j + 3 < ne) ? ep[j + 3] : -1;
        ushort2 u0, u1, u2, u3;
        if (n0 >= 0) u0 = *(const ushort2*)&x16[(size_t)(n0 & 0x1FFFF) * D + fp * 2];
        if (n1 >= 0) u1 = *(const ushort2*)&x16[(size_t)(n1 & 0x1FFFF) * D + fp * 2];
        if (n2 >= 0) u2 = *(const ushort2*)&x16[(size_t)(n2 & 0x1FFFF) * D + fp * 2];
        if (n3 >= 0) u3 = *(const ushort2*)&x16[(size_t)(n3 & 0x1FFFF) * D + fp * 2];
        if (n0 >= 0) { atomicAdd(&acc[n0 >> 17][fp * 2], bf2f(u0.x)); atomicAdd(&acc[n0 >> 17][fp * 2 + 1], bf2f(u0.y)); }
        if (n1 >= 0) { atomicAdd(&acc[n1 >> 17][fp * 2], bf2f(u1.x)); atomicAdd(&acc[n1 >> 17][fp * 2 + 1], bf2f(u1.y)); }
        if (n2 >= 0) { atomicAdd(&acc[n2 >> 17][fp * 2], bf2f(u2.x)); atomicAdd(&acc[n2 >> 17][fp * 2 + 1], bf2f(u2.y)); }
        if (n3 >= 0) { atomicAdd(&acc[n3 >> 17][fp * 2], bf2f(u3.x)); atomicAdd(&acc[n3 >> 17][fp * 2 + 1], bf2f(u3.y)); }
    }
    __syncthreads();

    // epilogue: out = acc + x (fp32), coalesced float4
    const float4* x4 = (const float4*)x;
    float4* o4 = (float4*)out;
    for (int q = t; q < 1024; q += 256) {
        int node = b * 64 + (q >> 4);
        if (node < N_NODES) {
            float4 a = ((const float4*)acc)[q];
            float4 xv = x4[(size_t)node * 16 + (q & 15)];
            a.x += xv.x; a.y += xv.y; a.z += xv.z; a.w += xv.w;
            o4[(size_t)node * 16 + (q & 15)] = a;
        }
    }
}

// ===========================================================================
// Tier-B fallback: CSR build + fp32 gather (R6-proven)
// ===========================================================================
__global__ __launch_bounds__(256) void k_histpos(const int* __restrict__ dst,
                                                 int* __restrict__ cnt,
                                                 int* __restrict__ pos) {
    int e = blockIdx.x * 256 + threadIdx.x;
    if (e < N_EDGES) pos[e] = atomicAdd(&cnt[dst[e]], 1);
}

__global__ __launch_bounds__(256) void k_fill2(const int* __restrict__ src,
                                               const int* __restrict__ dst,
                                               const int* __restrict__ pos,
                                               const int* __restrict__ ends,
                                               int* __restrict__ csr) {
    int e = blockIdx.x * 256 + threadIdx.x;
    if (e >= N_EDGES) return;
    int d = dst[e];
    int start = (d > 0) ? ends[d - 1] : 0;
    csr[start + pos[e]] = src[e];
}

__global__ __launch_bounds__(256) void k_agg(const float* __restrict__ x,
                                             const int* __restrict__ csr,
                                             const int* __restrict__ ends,
                                             float* __restrict__ out) {
    int node = blockIdx.x * 4 + (threadIdx.x >> 6);
    if (node >= N_NODES) return;
    int f = threadIdx.x & 63;
    int start = (node > 0) ? ends[node - 1] : 0;
    int end = ends[node];
    float a0 = x[(size_t)node * D + f], a1 = 0.f, a2 = 0.f, a3 = 0.f;
    int e = start;
    for (; e + 4 <= end; e += 4) {
        int s0 = csr[e], s1 = csr[e + 1], s2 = csr[e + 2], s3 = csr[e + 3];
        a0 += x[(size_t)s0 * D + f];
        a1 += x[(size_t)s1 * D + f];
        a2 += x[(size_t)s2 * D + f];
        a3 += x[(size_t)s3 * D + f];
    }
    for (; e < end; e++) a0 += x[(size_t)csr[e] * D + f];
    out[(size_t)node * D + f] = (a0 + a1) + (a2 + a3);
}

// ===========================================================================
// Tier-C fallback: atomic scatter (R2-proven)
// ===========================================================================
__global__ __launch_bounds__(256) void k_init(const float4* __restrict__ x4,
                                              float4* __restrict__ agg4, int n4) {
    int i = blockIdx.x * 256 + threadIdx.x;
    if (i < n4) agg4[i] = x4[i];
}

__global__ __launch_bounds__(256) void k_scatter(const float4* __restrict__ x4,
                                                 const int* __restrict__ src,
                                                 const int* __restrict__ dst,
                                                 float* __restrict__ agg) {
    int gid = blockIdx.x * 256 + threadIdx.x;
    int e = gid >> 4;
    if (e >= N_EDGES) return;
    int c = gid & 15;
    float4 v = x4[src[e] * 16 + c];
    float* p = agg + (size_t)dst[e] * D + c * 4;
    atomicAdd(p + 0, v.x);
    atomicAdd(p + 1, v.y);
    atomicAdd(p + 2, v.z);
    atomicAdd(p + 3, v.w);
}

// ===========================================================================
// MFMA bf16 fused MLP, in-place on d_out (R6-proven).
// ===========================================================================
__global__ __launch_bounds__(256) void k_mlp_mfma(float* __restrict__ io,
                                                  const float* __restrict__ W1,
                                                  const float* __restrict__ b1,
                                                  const float* __restrict__ W2,
                                                  const float* __restrict__ b2) {
    __shared__ unsigned short sW1b[8192];
    __shared__ unsigned short sW2b[8192];
    __shared__ float sh[4][16 * SH_STRIDE];
    __shared__ float sb1[H];
    __shared__ float sb2[D];

    int t = threadIdx.x;

    for (int q = t; q < 8192; q += 256) {
        int j = q & 7, l = (q >> 3) & 63, f = q >> 9;
        int nt = f & 7, kt = f >> 3;
        int k = kt * 32 + ((l >> 4) << 3) + j;
        int n = nt * 16 + (l & 15);
        sW1b[q] = f2bf(W1[k * H + n]);
    }
    for (int q = t; q < 8192; q += 256) {
        int j = q & 7, l = (q >> 3) & 63, f = q >> 9;
        int nt = f & 3, kt = f >> 2;
        int k = kt * 32 + ((l >> 4) << 3) + j;
        int n = nt * 16 + (l & 15);
        sW2b[q] = f2bf(W2[k * D + n]);
    }
    if (t < H) sb1[t] = b1[t];
    if (t >= H && t < H + D) sb2[t - H] = b2[t - H];
    __syncthreads();

    int w = t >> 6, l = t & 63;
    int m = l & 15, q4 = l >> 4;
    float* shw = sh[w];

    const int NT16 = N_NODES / 16;
    const int WAVES = MFMA_GRID * 4;
    const int ITERS = (NT16 + WAVES - 1) / WAVES;

    for (int it = 0; it < ITERS; ++it) {
        int tl = it * WAVES + blockIdx.x * 4 + w;
        bool valid = tl < NT16;
        int nbase = tl * 16;

        if (valid) {
            const float* xr = io + (size_t)(nbase + m) * D + q4 * 8;
            float4 a0 = *(const float4*)(xr);
            float4 a1 = *(const float4*)(xr + 4);
            float4 c0 = *(const float4*)(xr + 32);
            float4 c1 = *(const float4*)(xr + 36);
            short8 A0, A1;
            A0[0] = f2bf(a0.x); A0[1] = f2bf(a0.y); A0[2] = f2bf(a0.z); A0[3] = f2bf(a0.w);
            A0[4] = f2bf(a1.x); A0[5] = f2bf(a1.y); A0[6] = f2bf(a1.z); A0[7] = f2bf(a1.w);
            A1[0] = f2bf(c0.x); A1[1] = f2bf(c0.y); A1[2] = f2bf(c0.z); A1[3] = f2bf(c0.w);
            A1[4] = f2bf(c1.x); A1[5] = f2bf(c1.y); A1[6] = f2bf(c1.z); A1[7] = f2bf(c1.w);

#pragma unroll
            for (int nt = 0; nt < 8; nt++) {
                float bv = sb1[nt * 16 + m];
                floatx4 acc = {bv, bv, bv, bv};
                short8 B0 = *(const short8*)&sW1b[(0 * 8 + nt) * 512 + l * 8];
                short8 B1 = *(const short8*)&sW1b[(1 * 8 + nt) * 512 + l * 8];
                acc = __builtin_amdgcn_mfma_f32_16x16x32_bf16(A0, B0, acc, 0, 0, 0);
                acc = __builtin_amdgcn_mfma_f32_16x16x32_bf16(A1, B1, acc, 0, 0, 0);
#pragma unroll
                for (int r = 0; r < 4; r++)
                    shw[(q4 * 4 + r) * SH_STRIDE + nt * 16 + m] = fmaxf(acc[r], 0.f);
            }
        }
        __syncthreads();

        if (valid) {
            short8 Ah[4];
#pragma unroll
            for (int kt = 0; kt < 4; kt++) {
                const float* hr = &shw[m * SH_STRIDE + kt * 32 + q4 * 8];
                float4 h0 = *(const float4*)(hr);
                float4 h1 = *(const float4*)(hr + 4);
                Ah[kt][0] = f2bf(h0.x); Ah[kt][1] = f2bf(h0.y);
                Ah[kt][2] = f2bf(h0.z); Ah[kt][3] = f2bf(h0.w);
                Ah[kt][4] = f2bf(h1.x); Ah[kt][5] = f2bf(h1.y);
                Ah[kt][6] = f2bf(h1.z); Ah[kt][7] = f2bf(h1.w);
            }
#pragma unroll
            for (int nt = 0; nt < 4; nt++) {
                float bv = sb2[nt * 16 + m];
                floatx4 acc = {bv, bv, bv, bv};
#pragma unroll
                for (int kt = 0; kt < 4; kt++) {
                    short8 B = *(const short8*)&sW2b[(kt * 4 + nt) * 512 + l * 8];
                    acc = __builtin_amdgcn_mfma_f32_16x16x32_bf16(Ah[kt], B, acc, 0, 0, 0);
                }
#pragma unroll
                for (int r = 0; r < 4; r++)
                    io[(size_t)(nbase + q4 * 4 + r) * D + nt * 16 + m] = acc[r];
            }
        }
        __syncthreads();
    }
}

// ===========================================================================
extern "C" void kernel_launch(void* const* d_in, const int* in_sizes, int n_in,
                              void* d_out, int out_size, void* d_ws, size_t ws_size,
                              hipStream_t stream) {
    const float* x  = (const float*)d_in[0];
    const int* eidx = (const int*)d_in[1];   // [2, N_EDGES] int32 per harness
    const float* W1 = (const float*)d_in[2];
    const float* b1 = (const float*)d_in[3];
    const float* W2 = (const float*)d_in[4];
    const float* b2 = (const float*)d_in[5];
    float* out      = (float*)d_out;

    const int* src = eidx;
    const int* dst = eidx + N_EDGES;

    int ge = (N_EDGES + 255) / 256;
    int n4 = N_NODES * D / 4;

    // Tier A (bucket pipeline): x16[N*D bf16] ebuf[E] M2[NCHUNK*NB] colsum[NB]
    //                           bends[NB] bsum[512]           ~= 20.9 MB
    size_t need_A = (size_t)N_NODES * D * sizeof(unsigned short)
                  + (size_t)(N_EDGES + NCHUNK * NB + 2 * NB + 512) * sizeof(int);
    // Tier B: cnt[N] ends[N] bsum[512] pos[E] csr[E] (~13.6 MB)
    size_t need_B = (size_t)(2 * N_NODES + 512 + 2 * N_EDGES) * sizeof(int);

    if (ws_size >= need_A) {
        unsigned short* x16 = (unsigned short*)d_ws;
        int* ebuf   = (int*)(x16 + (size_t)N_NODES * D);
        int* M2     = ebuf + N_EDGES;
        int* colsum = M2 + NCHUNK * NB;
        int* bends  = colsum + NB;
        int* bsum   = bends + NB;

        k_xbf16<<<(n4 + 255) / 256, 256, 0, stream>>>((const float4*)x, (ushort4_t*)x16, n4);
        k_bhist<<<NCHUNK, 256, 0, stream>>>(dst, M2);
        k_rowscan<<<(NB + 15) / 16, 1024, 0, stream>>>(M2, colsum);
        int snb = (NB + SCAN_BS - 1) / SCAN_BS;          // 4
        k_scan1<<<snb, SCAN_BS, 0, stream>>>(colsum, bends, bsum, NB);
        k_scan2<<<1, 256, 0, stream>>>(bsum, snb);
        k_scan3<<<snb, SCAN_BS, 0, stream>>>(bends, bsum, NB);
        k_part<<<NCHUNK, 256, 0, stream>>>(src, dst, M2, bends, ebuf);
        k_bagg<<<NB, 256, 0, stream>>>(x, x16, ebuf, bends, out);
    } else if (ws_size >= need_B) {
        int* cnt  = (int*)d_ws;
        int* ends = cnt + N_NODES;
        int* bsum = ends + N_NODES;
        int* pos  = bsum + 512;
        int* csr  = pos + N_EDGES;

        k_zero<<<(N_NODES + 255) / 256, 256, 0, stream>>>(cnt, N_NODES);
        k_histpos<<<ge, 256, 0, stream>>>(dst, cnt, pos);
        k_scan1<<<SCAN_NBLK, SCAN_BS, 0, stream>>>(cnt, ends, bsum, N_NODES);
        k_scan2<<<1, 256, 0, stream>>>(bsum, SCAN_NBLK);
        k_scan3<<<SCAN_NBLK, SCAN_BS, 0, stream>>>(ends, bsum, N_NODES);
        k_fill2<<<ge, 256, 0, stream>>>(src, dst, pos, ends, csr);
        k_agg<<<(N_NODES + 3) / 4, 256, 0, stream>>>(x, csr, ends, out);
    } else {
        k_init<<<(n4 + 255) / 256, 256, 0, stream>>>((const float4*)x, (float4*)out, n4);
        long long total = (long long)N_EDGES * 16;
        k_scatter<<<(int)((total + 255) / 256), 256, 0, stream>>>(
            (const float4*)x, src, dst, out);
    }

    k_mlp_mfma<<<MFMA_GRID, 256, 0, stream>>>(out, W1, b1, W2, b2);
}

// Round 10
// 204.477 us; speedup vs baseline: 3.7185x; 3.7185x over previous
//
#include <hip/hip_runtime.h>

#define N_NODES 100000
#define N_EDGES 1600000
#define D 64
#define H 128
#define SCAN_BS 512
#define SCAN_NBLK ((N_NODES + SCAN_BS - 1) / SCAN_BS)   // 196

// bucket pipeline
#define NB 1563                  // buckets of 64 nodes: 1563*64 >= 100000
#define NCHUNK 256
#define EPC (N_EDGES / NCHUNK)   // 6250 exactly
#define BCAP 2560                // LDS edge cap per bucket (avg 1024, sigma ~32)
#define OVF_CAP 4096

#define MFMA_GRID 512
#define SH_STRIDE 132

typedef __attribute__((ext_vector_type(8))) short short8;
typedef __attribute__((ext_vector_type(4))) float floatx4;
typedef __attribute__((ext_vector_type(4))) unsigned short ushort4_t;

__device__ __forceinline__ unsigned short f2bf(float f) {
    unsigned u = __builtin_bit_cast(unsigned, f);
    u += 0x7FFFu + ((u >> 16) & 1u);
    return (unsigned short)(u >> 16);
}
__device__ __forceinline__ float bf2f(unsigned short u) {
    unsigned v = ((unsigned)u) << 16;
    return __builtin_bit_cast(float, v);
}

// ===========================================================================
__global__ __launch_bounds__(256) void k_zero(int* __restrict__ p, int n) {
    int i = blockIdx.x * 256 + threadIdx.x;
    if (i < n) p[i] = 0;
}

__global__ __launch_bounds__(256) void k_xbf16(const float4* __restrict__ x4,
                                               ushort4_t* __restrict__ y, int n4) {
    int i = blockIdx.x * 256 + threadIdx.x;
    if (i >= n4) return;
    float4 v = x4[i];
    ushort4_t o;
    o[0] = f2bf(v.x); o[1] = f2bf(v.y); o[2] = f2bf(v.z); o[3] = f2bf(v.w);
    y[i] = o;
}

// ===========================================================================
// P1: per-chunk bucket histogram in LDS -> M2[chunk][bucket] (coalesced).
// Also zeroes the overflow counter (block 0).
// ===========================================================================
__global__ __launch_bounds__(256) void k_bhist(const int* __restrict__ dst,
                                               int* __restrict__ M2,
                                               int* __restrict__ ovfn) {
    __shared__ int hist[NB];
    int t = threadIdx.x, c = blockIdx.x;
    if (c == 0 && t == 0) ovfn[0] = 0;
    for (int i = t; i < NB; i += 256) hist[i] = 0;
    __syncthreads();
    const int* dp = dst + c * EPC;
    for (int i = t; i < EPC; i += 256) atomicAdd(&hist[dp[i] >> 6], 1);
    __syncthreads();
    int* mp = M2 + c * NB;
    for (int i = t; i < NB; i += 256) mp[i] = hist[i];
}

// ===========================================================================
// S1: column-wise exclusive scan of M2 (rows=chunks, cols=buckets), fully
// coalesced: one thread per bucket-column, running sum over the 256 rows.
// ===========================================================================
__global__ __launch_bounds__(256) void k_colscan(int* __restrict__ M2,
                                                 int* __restrict__ colsum) {
    int b = blockIdx.x * 256 + threadIdx.x;
    if (b >= NB) return;
    int run = 0;
    for (int c = 0; c < NCHUNK; c++) {
        int v = M2[c * NB + b];
        M2[c * NB + b] = run;
        run += v;
    }
    colsum[b] = run;
}

// ===========================================================================
// parametric inclusive scan (3 phases)
// ===========================================================================
__global__ __launch_bounds__(SCAN_BS) void k_scan1(const int* __restrict__ cnt,
                                                   int* __restrict__ ends,
                                                   int* __restrict__ bsum, int n) {
    __shared__ int s[SCAN_BS];
    int t = threadIdx.x, b = blockIdx.x;
    int id = b * SCAN_BS + t;
    s[t] = (id < n) ? cnt[id] : 0;
    __syncthreads();
    for (int off = 1; off < SCAN_BS; off <<= 1) {
        int u = (t >= off) ? s[t - off] : 0;
        __syncthreads();
        s[t] += u;
        __syncthreads();
    }
    if (id < n) ends[id] = s[t];
    if (t == SCAN_BS - 1) bsum[b] = s[t];
}

__global__ __launch_bounds__(256) void k_scan2(int* __restrict__ bsum, int nb) {
    __shared__ int s[256];
    int t = threadIdx.x;
    s[t] = (t < nb) ? bsum[t] : 0;
    __syncthreads();
    for (int off = 1; off < 256; off <<= 1) {
        int u = (t >= off) ? s[t - off] : 0;
        __syncthreads();
        s[t] += u;
        __syncthreads();
    }
    if (t < nb) bsum[t] = s[t];
}

__global__ __launch_bounds__(SCAN_BS) void k_scan3(int* __restrict__ ends,
                                                   const int* __restrict__ bsum, int n) {
    int t = threadIdx.x, b = blockIdx.x;
    int id = b * SCAN_BS + t;
    if (b > 0 && id < n) ends[id] += bsum[b - 1];
}

// ===========================================================================
// P3: partition edges into bucket-ordered ebuf, packed (dlow<<17)|src.
// LDS cursor atomics only; slice-exclusive global writes. (R9-proven)
// ===========================================================================
__global__ __launch_bounds__(256) void k_part(const int* __restrict__ src,
                                              const int* __restrict__ dst,
                                              const int* __restrict__ M2,
                                              const int* __restrict__ bends,
                                              int* __restrict__ ebuf) {
    __shared__ int cur[NB];
    int t = threadIdx.x, c = blockIdx.x;
    const int* mp = M2 + c * NB;
    for (int i = t; i < NB; i += 256)
        cur[i] = ((i > 0) ? bends[i - 1] : 0) + mp[i];
    __syncthreads();
    const int* sp = src + c * EPC;
    const int* dp = dst + c * EPC;
    for (int i = t; i < EPC; i += 256) {
        int d = dp[i], s = sp[i];
        int p = atomicAdd(&cur[d >> 6], 1);
        ebuf[p] = s | ((d & 63) << 17);
    }
}

// ===========================================================================
// P4: one block per bucket. Build 64-node mini-CSR in LDS (int atomics on 64
// counters + one wave-scan), then node-per-wave register-accum gather:
// quarter-wave per edge, ushort4/lane (16 lanes = one 128B bf16 row),
// unroll 2 -> 8 rows in flight per wave; shfl_xor(16/32) reduce; fp32 +x
// epilogue. NO float atomics anywhere.
// ===========================================================================
__global__ __launch_bounds__(256) void k_bagg2(const float* __restrict__ x,
                                               const unsigned short* __restrict__ x16,
                                               const int* __restrict__ ebuf,
                                               const int* __restrict__ bends,
                                               int* __restrict__ ovfn,
                                               int* __restrict__ ovf,
                                               float* __restrict__ out) {
    __shared__ int scur[64];
    __shared__ int snd[64];          // inclusive ends per dlow
    __shared__ int slist[BCAP];
    int t = threadIdx.x, b = blockIdx.x;
    int estart = (b > 0) ? bends[b - 1] : 0;
    int ne = bends[b] - estart;
    const int* ep = ebuf + estart;

    if (t < 64) scur[t] = 0;
    __syncthreads();
    for (int i = t; i < ne; i += 256) atomicAdd(&scur[ep[i] >> 17], 1);
    __syncthreads();
    if (t < 64) {
        int v = scur[t], s = v;
#pragma unroll
        for (int off = 1; off < 64; off <<= 1) {
            int u = __shfl_up(s, off, 64);
            if (t >= off) s += u;
        }
        snd[t] = s;
        scur[t] = s - v;             // exclusive start -> cursor
    }
    __syncthreads();
    for (int i = t; i < ne; i += 256) {
        int v = ep[i];
        int p = atomicAdd(&scur[v >> 17], 1);
        if (p < BCAP) {
            slist[p] = v & 0x1FFFF;
        } else {                     // practically never (Poisson(1024))
            int o = atomicAdd(ovfn, 1);
            if (o < OVF_CAP) { ovf[2 * o] = b * 64 + (v >> 17); ovf[2 * o + 1] = v & 0x1FFFF; }
        }
    }
    __syncthreads();

    int w = t >> 6, l = t & 63;
    int q = l >> 4, f4 = l & 15;
    for (int nn = 0; nn < 16; nn++) {
        int dlow = w * 16 + nn;
        int node = b * 64 + dlow;
        int s0 = (dlow > 0) ? snd[dlow - 1] : 0;
        int e1 = snd[dlow];
        if (s0 > BCAP) s0 = BCAP;
        if (e1 > BCAP) e1 = BCAP;    // clipped edges live in ovf
        float4 a = make_float4(0.f, 0.f, 0.f, 0.f);
        float4 a2 = make_float4(0.f, 0.f, 0.f, 0.f);
        int i = s0 + q;
        for (; i + 4 < e1; i += 8) {
            int sA = slist[i];
            int sB = slist[i + 4];
            ushort4_t uA = *(const ushort4_t*)&x16[(size_t)sA * D + f4 * 4];
            ushort4_t uB = *(const ushort4_t*)&x16[(size_t)sB * D + f4 * 4];
            a.x  += bf2f(uA[0]); a.y  += bf2f(uA[1]); a.z  += bf2f(uA[2]); a.w  += bf2f(uA[3]);
            a2.x += bf2f(uB[0]); a2.y += bf2f(uB[1]); a2.z += bf2f(uB[2]); a2.w += bf2f(uB[3]);
        }
        if (i < e1) {
            int sA = slist[i];
            ushort4_t uA = *(const ushort4_t*)&x16[(size_t)sA * D + f4 * 4];
            a.x += bf2f(uA[0]); a.y += bf2f(uA[1]); a.z += bf2f(uA[2]); a.w += bf2f(uA[3]);
        }
        a.x += a2.x; a.y += a2.y; a.z += a2.z; a.w += a2.w;
        a.x += __shfl_xor(a.x, 16); a.y += __shfl_xor(a.y, 16);
        a.z += __shfl_xor(a.z, 16); a.w += __shfl_xor(a.w, 16);
        a.x += __shfl_xor(a.x, 32); a.y += __shfl_xor(a.y, 32);
        a.z += __shfl_xor(a.z, 32); a.w += __shfl_xor(a.w, 32);
        if (q == 0 && node < N_NODES) {
            float4 xv = *(const float4*)&x[(size_t)node * D + f4 * 4];
            float4 o;
            o.x = a.x + xv.x; o.y = a.y + xv.y; o.z = a.z + xv.z; o.w = a.w + xv.w;
            *(float4*)&out[(size_t)node * D + f4 * 4] = o;
        }
    }
}

// overflow cleanup (normally *ovfn == 0)
__global__ __launch_bounds__(256) void k_ovf(const int* __restrict__ ovfn,
                                             const int* __restrict__ ovf,
                                             const float* __restrict__ x,
                                             float* __restrict__ out) {
    int n = *ovfn;
    if (n > OVF_CAP) n = OVF_CAP;
    int f = threadIdx.x & 63;
    for (int idx = threadIdx.x >> 6; idx < n; idx += 4) {
        int d = ovf[2 * idx], s = ovf[2 * idx + 1];
        atomicAdd(&out[(size_t)d * D + f], x[(size_t)s * D + f]);
    }
}

// ===========================================================================
// Tier-B fallback: CSR build + fp32 gather (R6/R8-proven)
// ===========================================================================
__global__ __launch_bounds__(256) void k_histpos(const int* __restrict__ dst,
                                                 int* __restrict__ cnt,
                                                 int* __restrict__ pos) {
    int e = blockIdx.x * 256 + threadIdx.x;
    if (e < N_EDGES) pos[e] = atomicAdd(&cnt[dst[e]], 1);
}

__global__ __launch_bounds__(256) void k_fill2(const int* __restrict__ src,
                                               const int* __restrict__ dst,
                                               const int* __restrict__ pos,
                                               const int* __restrict__ ends,
                                               int* __restrict__ csr) {
    int e = blockIdx.x * 256 + threadIdx.x;
    if (e >= N_EDGES) return;
    int d = dst[e];
    int start = (d > 0) ? ends[d - 1] : 0;
    csr[start + pos[e]] = src[e];
}

__global__ __launch_bounds__(256) void k_agg(const float* __restrict__ x,
                                             const int* __restrict__ csr,
                                             const int* __restrict__ ends,
                                             float* __restrict__ out) {
    int node = blockIdx.x * 4 + (threadIdx.x >> 6);
    if (node >= N_NODES) return;
    int f = threadIdx.x & 63;
    int start = (node > 0) ? ends[node - 1] : 0;
    int end = ends[node];
    float a0 = x[(size_t)node * D + f], a1 = 0.f, a2 = 0.f, a3 = 0.f;
    int e = start;
    for (; e + 4 <= end; e += 4) {
        int s0 = csr[e], s1 = csr[e + 1], s2 = csr[e + 2], s3 = csr[e + 3];
        a0 += x[(size_t)s0 * D + f];
        a1 += x[(size_t)s1 * D + f];
        a2 += x[(size_t)s2 * D + f];
        a3 += x[(size_t)s3 * D + f];
    }
    for (; e < end; e++) a0 += x[(size_t)csr[e] * D + f];
    out[(size_t)node * D + f] = (a0 + a1) + (a2 + a3);
}

// ===========================================================================
// Tier-C fallback: atomic scatter (R2-proven)
// ===========================================================================
__global__ __launch_bounds__(256) void k_init(const float4* __restrict__ x4,
                                              float4* __restrict__ agg4, int n4) {
    int i = blockIdx.x * 256 + threadIdx.x;
    if (i < n4) agg4[i] = x4[i];
}

__global__ __launch_bounds__(256) void k_scatter(const float4* __restrict__ x4,
                                                 const int* __restrict__ src,
                                                 const int* __restrict__ dst,
                                                 float* __restrict__ agg) {
    int gid = blockIdx.x * 256 + threadIdx.x;
    int e = gid >> 4;
    if (e >= N_EDGES) return;
    int c = gid & 15;
    float4 v = x4[src[e] * 16 + c];
    float* p = agg + (size_t)dst[e] * D + c * 4;
    atomicAdd(p + 0, v.x);
    atomicAdd(p + 1, v.y);
    atomicAdd(p + 2, v.z);
    atomicAdd(p + 3, v.w);
}

// ===========================================================================
// MFMA bf16 fused MLP, in-place on d_out (R6-proven).
// ===========================================================================
__global__ __launch_bounds__(256) void k_mlp_mfma(float* __restrict__ io,
                                                  const float* __restrict__ W1,
                                                  const float* __restrict__ b1,
                                                  const float* __restrict__ W2,
                                                  const float* __restrict__ b2) {
    __shared__ unsigned short sW1b[8192];
    __shared__ unsigned short sW2b[8192];
    __shared__ float sh[4][16 * SH_STRIDE];
    __shared__ float sb1[H];
    __shared__ float sb2[D];

    int t = threadIdx.x;

    for (int q = t; q < 8192; q += 256) {
        int j = q & 7, l = (q >> 3) & 63, f = q >> 9;
        int nt = f & 7, kt = f >> 3;
        int k = kt * 32 + ((l >> 4) << 3) + j;
        int n = nt * 16 + (l & 15);
        sW1b[q] = f2bf(W1[k * H + n]);
    }
    for (int q = t; q < 8192; q += 256) {
        int j = q & 7, l = (q >> 3) & 63, f = q >> 9;
        int nt = f & 3, kt = f >> 2;
        int k = kt * 32 + ((l >> 4) << 3) + j;
        int n = nt * 16 + (l & 15);
        sW2b[q] = f2bf(W2[k * D + n]);
    }
    if (t < H) sb1[t] = b1[t];
    if (t >= H && t < H + D) sb2[t - H] = b2[t - H];
    __syncthreads();

    int w = t >> 6, l = t & 63;
    int m = l & 15, q4 = l >> 4;
    float* shw = sh[w];

    const int NT16 = N_NODES / 16;
    const int WAVES = MFMA_GRID * 4;
    const int ITERS = (NT16 + WAVES - 1) / WAVES;

    for (int it = 0; it < ITERS; ++it) {
        int tl = it * WAVES + blockIdx.x * 4 + w;
        bool valid = tl < NT16;
        int nbase = tl * 16;

        if (valid) {
            const float* xr = io + (size_t)(nbase + m) * D + q4 * 8;
            float4 a0 = *(const float4*)(xr);
            float4 a1 = *(const float4*)(xr + 4);
            float4 c0 = *(const float4*)(xr + 32);
            float4 c1 = *(const float4*)(xr + 36);
            short8 A0, A1;
            A0[0] = f2bf(a0.x); A0[1] = f2bf(a0.y); A0[2] = f2bf(a0.z); A0[3] = f2bf(a0.w);
            A0[4] = f2bf(a1.x); A0[5] = f2bf(a1.y); A0[6] = f2bf(a1.z); A0[7] = f2bf(a1.w);
            A1[0] = f2bf(c0.x); A1[1] = f2bf(c0.y); A1[2] = f2bf(c0.z); A1[3] = f2bf(c0.w);
            A1[4] = f2bf(c1.x); A1[5] = f2bf(c1.y); A1[6] = f2bf(c1.z); A1[7] = f2bf(c1.w);

#pragma unroll
            for (int nt = 0; nt < 8; nt++) {
                float bv = sb1[nt * 16 + m];
                floatx4 acc = {bv, bv, bv, bv};
                short8 B0 = *(const short8*)&sW1b[(0 * 8 + nt) * 512 + l * 8];
                short8 B1 = *(const short8*)&sW1b[(1 * 8 + nt) * 512 + l * 8];
                acc = __builtin_amdgcn_mfma_f32_16x16x32_bf16(A0, B0, acc, 0, 0, 0);
                acc = __builtin_amdgcn_mfma_f32_16x16x32_bf16(A1, B1, acc, 0, 0, 0);
#pragma unroll
                for (int r = 0; r < 4; r++)
                    shw[(q4 * 4 + r) * SH_STRIDE + nt * 16 + m] = fmaxf(acc[r], 0.f);
            }
        }
        __syncthreads();

        if (valid) {
            short8 Ah[4];
#pragma unroll
            for (int kt = 0; kt < 4; kt++) {
                const float* hr = &shw[m * SH_STRIDE + kt * 32 + q4 * 8];
                float4 h0 = *(const float4*)(hr);
                float4 h1 = *(const float4*)(hr + 4);
                Ah[kt][0] = f2bf(h0.x); Ah[kt][1] = f2bf(h0.y);
                Ah[kt][2] = f2bf(h0.z); Ah[kt][3] = f2bf(h0.w);
                Ah[kt][4] = f2bf(h1.x); Ah[kt][5] = f2bf(h1.y);
                Ah[kt][6] = f2bf(h1.z); Ah[kt][7] = f2bf(h1.w);
            }
#pragma unroll
            for (int nt = 0; nt < 4; nt++) {
                float bv = sb2[nt * 16 + m];
                floatx4 acc = {bv, bv, bv, bv};
#pragma unroll
                for (int kt = 0; kt < 4; kt++) {
                    short8 B = *(const short8*)&sW2b[(kt * 4 + nt) * 512 + l * 8];
                    acc = __builtin_amdgcn_mfma_f32_16x16x32_bf16(Ah[kt], B, acc, 0, 0, 0);
                }
#pragma unroll
                for (int r = 0; r < 4; r++)
                    io[(size_t)(nbase + q4 * 4 + r) * D + nt * 16 + m] = acc[r];
            }
        }
        __syncthreads();
    }
}

// ===========================================================================
extern "C" void kernel_launch(void* const* d_in, const int* in_sizes, int n_in,
                              void* d_out, int out_size, void* d_ws, size_t ws_size,
                              hipStream_t stream) {
    const float* x  = (const float*)d_in[0];
    const int* eidx = (const int*)d_in[1];   // [2, N_EDGES] int32 per harness
    const float* W1 = (const float*)d_in[2];
    const float* b1 = (const float*)d_in[3];
    const float* W2 = (const float*)d_in[4];
    const float* b2 = (const float*)d_in[5];
    float* out      = (float*)d_out;

    const int* src = eidx;
    const int* dst = eidx + N_EDGES;

    int ge = (N_EDGES + 255) / 256;
    int n4 = N_NODES * D / 4;

    // Tier A: x16[N*D bf16] ebuf[E] M2[NCHUNK*NB] colsum[NB] bends[NB]
    //         bsum[512] ovfn[4] ovf[2*OVF_CAP]            ~= 20.9 MB
    size_t need_A = (size_t)N_NODES * D * sizeof(unsigned short)
                  + (size_t)(N_EDGES + NCHUNK * NB + 2 * NB + 512 + 4 + 2 * OVF_CAP) * sizeof(int);
    // Tier B: cnt[N] ends[N] bsum[512] pos[E] csr[E] (~13.6 MB)
    size_t need_B = (size_t)(2 * N_NODES + 512 + 2 * N_EDGES) * sizeof(int);

    if (ws_size >= need_A) {
        unsigned short* x16 = (unsigned short*)d_ws;
        int* ebuf   = (int*)(x16 + (size_t)N_NODES * D);
        int* M2     = ebuf + N_EDGES;
        int* colsum = M2 + NCHUNK * NB;
        int* bends  = colsum + NB;
        int* bsum   = bends + NB;
        int* ovfn   = bsum + 512;
        int* ovf    = ovfn + 4;

        k_xbf16<<<(n4 + 255) / 256, 256, 0, stream>>>((const float4*)x, (ushort4_t*)x16, n4);
        k_bhist<<<NCHUNK, 256, 0, stream>>>(dst, M2, ovfn);
        k_colscan<<<(NB + 255) / 256, 256, 0, stream>>>(M2, colsum);
        int snb = (NB + SCAN_BS - 1) / SCAN_BS;          // 4
        k_scan1<<<snb, SCAN_BS, 0, stream>>>(colsum, bends, bsum, NB);
        k_scan2<<<1, 256, 0, stream>>>(bsum, snb);
        k_scan3<<<snb, SCAN_BS, 0, stream>>>(bends, bsum, NB);
        k_part<<<NCHUNK, 256, 0, stream>>>(src, dst, M2, bends, ebuf);
        k_bagg2<<<NB, 256, 0, stream>>>(x, x16, ebuf, bends, ovfn, ovf, out);
        k_ovf<<<1, 256, 0, stream>>>(ovfn, ovf, x, out);
    } else if (ws_size >= need_B) {
        int* cnt  = (int*)d_ws;
        int* ends = cnt + N_NODES;
        int* bsum = ends + N_NODES;
        int* pos  = bsum + 512;
        int* csr  = pos + N_EDGES;

        k_zero<<<(N_NODES + 255) / 256, 256, 0, stream>>>(cnt, N_NODES);
        k_histpos<<<ge, 256, 0, stream>>>(dst, cnt, pos);
        k_scan1<<<SCAN_NBLK, SCAN_BS, 0, stream>>>(cnt, ends, bsum, N_NODES);
        k_scan2<<<1, 256, 0, stream>>>(bsum, SCAN_NBLK);
        k_scan3<<<SCAN_NBLK, SCAN_BS, 0, stream>>>(ends, bsum, N_NODES);
        k_fill2<<<ge, 256, 0, stream>>>(src, dst, pos, ends, csr);
        k_agg<<<(N_NODES + 3) / 4, 256, 0, stream>>>(x, csr, ends, out);
    } else {
        k_init<<<(n4 + 255) / 256, 256, 0, stream>>>((const float4*)x, (float4*)out, n4);
        long long total = (long long)N_EDGES * 16;
        k_scatter<<<(int)((total + 255) / 256), 256, 0, stream>>>(
            (const float4*)x, src, dst, out);
    }

    k_mlp_mfma<<<MFMA_GRID, 256, 0, stream>>>(out, W1, b1, W2, b2);
}

// Round 11
// 199.088 us; speedup vs baseline: 3.8192x; 1.0271x over previous
//
#include <hip/hip_runtime.h>

#define N_NODES 100000
#define N_EDGES 1600000
#define D 64
#define H 128
#define SCAN_BS 512
#define SCAN_NBLK ((N_NODES + SCAN_BS - 1) / SCAN_BS)   // 196

// bucket pipeline
#define NB 1563                  // buckets of 64 nodes: 1563*64 >= 100000
#define NCHUNK 256
#define EPC (N_EDGES / NCHUNK)   // 6250 exactly
#define BCAP 2560                // LDS edge cap per bucket (avg 1024)
#define OVF_CAP 4096

#define MFMA_GRID 512
#define SH_STRIDE 132

typedef __attribute__((ext_vector_type(8))) short short8;
typedef __attribute__((ext_vector_type(4))) float floatx4;
typedef __attribute__((ext_vector_type(4))) unsigned short ushort4_t;

__device__ __forceinline__ unsigned short f2bf(float f) {
    unsigned u = __builtin_bit_cast(unsigned, f);
    u += 0x7FFFu + ((u >> 16) & 1u);
    return (unsigned short)(u >> 16);
}
__device__ __forceinline__ float bf2f(unsigned short u) {
    unsigned v = ((unsigned)u) << 16;
    return __builtin_bit_cast(float, v);
}

// ===========================================================================
__global__ __launch_bounds__(256) void k_zero(int* __restrict__ p, int n) {
    int i = blockIdx.x * 256 + threadIdx.x;
    if (i < n) p[i] = 0;
}

__global__ __launch_bounds__(256) void k_xbf16(const float4* __restrict__ x4,
                                               ushort4_t* __restrict__ y, int n4) {
    int i = blockIdx.x * 256 + threadIdx.x;
    if (i >= n4) return;
    float4 v = x4[i];
    ushort4_t o;
    o[0] = f2bf(v.x); o[1] = f2bf(v.y); o[2] = f2bf(v.z); o[3] = f2bf(v.w);
    y[i] = o;
}

// ===========================================================================
// P1: per-chunk bucket histogram in LDS -> M2[chunk][bucket] (coalesced).
// ===========================================================================
__global__ __launch_bounds__(256) void k_bhist(const int* __restrict__ dst,
                                               int* __restrict__ M2,
                                               int* __restrict__ ovfn) {
    __shared__ int hist[NB];
    int t = threadIdx.x, c = blockIdx.x;
    if (c == 0 && t == 0) ovfn[0] = 0;
    for (int i = t; i < NB; i += 256) hist[i] = 0;
    __syncthreads();
    const int* dp = dst + c * EPC;
    for (int i = t; i < EPC; i += 256) atomicAdd(&hist[dp[i] >> 6], 1);
    __syncthreads();
    int* mp = M2 + c * NB;
    for (int i = t; i < NB; i += 256) mp[i] = hist[i];
}

// ===========================================================================
// S1: column-wise exclusive scan of M2, coalesced (thread per bucket-column).
// ===========================================================================
__global__ __launch_bounds__(256) void k_colscan(int* __restrict__ M2,
                                                 int* __restrict__ colsum) {
    int b = blockIdx.x * 256 + threadIdx.x;
    if (b >= NB) return;
    int run = 0;
    for (int c = 0; c < NCHUNK; c++) {
        int v = M2[c * NB + b];
        M2[c * NB + b] = run;
        run += v;
    }
    colsum[b] = run;
}

// ===========================================================================
// S2: single-block inclusive scan of colsum[NB] -> bends[NB].
// 512 threads, 4 elems/thread local prefix + Hillis-Steele over partials.
// ===========================================================================
__global__ __launch_bounds__(512) void k_bscan(const int* __restrict__ colsum,
                                               int* __restrict__ bends) {
    __shared__ int part[512];
    int t = threadIdx.x;
    int i0 = t * 4;
    int v0 = (i0 + 0 < NB) ? colsum[i0 + 0] : 0;
    int v1 = (i0 + 1 < NB) ? colsum[i0 + 1] : 0;
    int v2 = (i0 + 2 < NB) ? colsum[i0 + 2] : 0;
    int v3 = (i0 + 3 < NB) ? colsum[i0 + 3] : 0;
    int r0 = v0, r1 = r0 + v1, r2 = r1 + v2, r3 = r2 + v3;
    part[t] = r3;
    __syncthreads();
    for (int off = 1; off < 512; off <<= 1) {
        int u = (t >= off) ? part[t - off] : 0;
        __syncthreads();
        part[t] += u;
        __syncthreads();
    }
    int base = (t > 0) ? part[t - 1] : 0;
    if (i0 + 0 < NB) bends[i0 + 0] = base + r0;
    if (i0 + 1 < NB) bends[i0 + 1] = base + r1;
    if (i0 + 2 < NB) bends[i0 + 2] = base + r2;
    if (i0 + 3 < NB) bends[i0 + 3] = base + r3;
}

// ===========================================================================
// P3: partition edges into bucket-ordered ebuf, packed (dlow<<17)|src.
// LDS cursor atomics only; slice-exclusive global writes. (R9/R10-proven)
// ===========================================================================
__global__ __launch_bounds__(256) void k_part(const int* __restrict__ src,
                                              const int* __restrict__ dst,
                                              const int* __restrict__ M2,
                                              const int* __restrict__ bends,
                                              int* __restrict__ ebuf) {
    __shared__ int cur[NB];
    int t = threadIdx.x, c = blockIdx.x;
    const int* mp = M2 + c * NB;
    for (int i = t; i < NB; i += 256)
        cur[i] = ((i > 0) ? bends[i - 1] : 0) + mp[i];
    __syncthreads();
    const int* sp = src + c * EPC;
    const int* dp = dst + c * EPC;
    for (int i = t; i < EPC; i += 256) {
        int d = dp[i], s = sp[i];
        int p = atomicAdd(&cur[d >> 6], 1);
        ebuf[p] = s | ((d & 63) << 17);
    }
}

// ===========================================================================
// P4: one block per bucket. Build 64-node mini-CSR in LDS, then QUARTER-WAVE
// PER NODE register-accum gather: lane f4 owns features 4f4..4f4+3 across the
// node's whole edge list -> NO cross-lane reduction; unroll-4 edge loop
// -> 16 rows in flight per wave. Coalesced fp32 +x epilogue. No float atomics.
// ===========================================================================
__global__ __launch_bounds__(256) void k_bagg3(const float* __restrict__ x,
                                               const unsigned short* __restrict__ x16,
                                               const int* __restrict__ ebuf,
                                               const int* __restrict__ bends,
                                               int* __restrict__ ovfn,
                                               int* __restrict__ ovf,
                                               float* __restrict__ out) {
    __shared__ int scur[64];
    __shared__ int snd[64];          // inclusive ends per dlow
    __shared__ int slist[BCAP];
    int t = threadIdx.x, b = blockIdx.x;
    int estart = (b > 0) ? bends[b - 1] : 0;
    int ne = bends[b] - estart;
    const int* ep = ebuf + estart;

    if (t < 64) scur[t] = 0;
    __syncthreads();
    for (int i = t; i < ne; i += 256) atomicAdd(&scur[ep[i] >> 17], 1);
    __syncthreads();
    if (t < 64) {
        int v = scur[t], s = v;
#pragma unroll
        for (int off = 1; off < 64; off <<= 1) {
            int u = __shfl_up(s, off, 64);
            if (t >= off) s += u;
        }
        snd[t] = s;
        scur[t] = s - v;             // exclusive start -> cursor
    }
    __syncthreads();
    for (int i = t; i < ne; i += 256) {
        int v = ep[i];
        int p = atomicAdd(&scur[v >> 17], 1);
        if (p < BCAP) {
            slist[p] = v & 0x1FFFF;
        } else {                     // practically never (Poisson(1024))
            int o = atomicAdd(ovfn, 1);
            if (o < OVF_CAP) { ovf[2 * o] = b * 64 + (v >> 17); ovf[2 * o + 1] = v & 0x1FFFF; }
        }
    }
    __syncthreads();

    int qw = t >> 4;                 // quarter-wave 0..15
    int f4 = t & 15;                 // feature quad
#pragma unroll
    for (int k = 0; k < 4; k++) {
        int dlow = qw * 4 + k;
        int node = b * 64 + dlow;
        int s0 = (dlow > 0) ? snd[dlow - 1] : 0;
        int e1 = snd[dlow];
        if (s0 > BCAP) s0 = BCAP;
        if (e1 > BCAP) e1 = BCAP;    // clipped edges live in ovf
        float4 a0 = make_float4(0.f, 0.f, 0.f, 0.f);
        float4 a1 = a0, a2 = a0, a3 = a0;
        int i = s0;
        for (; i + 4 <= e1; i += 4) {
            int sA = slist[i], sB = slist[i + 1], sC = slist[i + 2], sD = slist[i + 3];
            ushort4_t uA = *(const ushort4_t*)&x16[(size_t)sA * D + f4 * 4];
            ushort4_t uB = *(const ushort4_t*)&x16[(size_t)sB * D + f4 * 4];
            ushort4_t uC = *(const ushort4_t*)&x16[(size_t)sC * D + f4 * 4];
            ushort4_t uD = *(const ushort4_t*)&x16[(size_t)sD * D + f4 * 4];
            a0.x += bf2f(uA[0]); a0.y += bf2f(uA[1]); a0.z += bf2f(uA[2]); a0.w += bf2f(uA[3]);
            a1.x += bf2f(uB[0]); a1.y += bf2f(uB[1]); a1.z += bf2f(uB[2]); a1.w += bf2f(uB[3]);
            a2.x += bf2f(uC[0]); a2.y += bf2f(uC[1]); a2.z += bf2f(uC[2]); a2.w += bf2f(uC[3]);
            a3.x += bf2f(uD[0]); a3.y += bf2f(uD[1]); a3.z += bf2f(uD[2]); a3.w += bf2f(uD[3]);
        }
        for (; i < e1; i++) {
            int sA = slist[i];
            ushort4_t uA = *(const ushort4_t*)&x16[(size_t)sA * D + f4 * 4];
            a0.x += bf2f(uA[0]); a0.y += bf2f(uA[1]); a0.z += bf2f(uA[2]); a0.w += bf2f(uA[3]);
        }
        a0.x = (a0.x + a1.x) + (a2.x + a3.x);
        a0.y = (a0.y + a1.y) + (a2.y + a3.y);
        a0.z = (a0.z + a1.z) + (a2.z + a3.z);
        a0.w = (a0.w + a1.w) + (a2.w + a3.w);
        if (node < N_NODES) {
            float4 xv = *(const float4*)&x[(size_t)node * D + f4 * 4];
            float4 o;
            o.x = a0.x + xv.x; o.y = a0.y + xv.y; o.z = a0.z + xv.z; o.w = a0.w + xv.w;
            *(float4*)&out[(size_t)node * D + f4 * 4] = o;
        }
    }
}

// overflow cleanup (normally *ovfn == 0)
__global__ __launch_bounds__(256) void k_ovf(const int* __restrict__ ovfn,
                                             const int* __restrict__ ovf,
                                             const float* __restrict__ x,
                                             float* __restrict__ out) {
    int n = *ovfn;
    if (n > OVF_CAP) n = OVF_CAP;
    int f = threadIdx.x & 63;
    for (int idx = threadIdx.x >> 6; idx < n; idx += 4) {
        int d = ovf[2 * idx], s = ovf[2 * idx + 1];
        atomicAdd(&out[(size_t)d * D + f], x[(size_t)s * D + f]);
    }
}

// ===========================================================================
// parametric inclusive scan (3 phases) — Tier-B fallback only
// ===========================================================================
__global__ __launch_bounds__(SCAN_BS) void k_scan1(const int* __restrict__ cnt,
                                                   int* __restrict__ ends,
                                                   int* __restrict__ bsum, int n) {
    __shared__ int s[SCAN_BS];
    int t = threadIdx.x, b = blockIdx.x;
    int id = b * SCAN_BS + t;
    s[t] = (id < n) ? cnt[id] : 0;
    __syncthreads();
    for (int off = 1; off < SCAN_BS; off <<= 1) {
        int u = (t >= off) ? s[t - off] : 0;
        __syncthreads();
        s[t] += u;
        __syncthreads();
    }
    if (id < n) ends[id] = s[t];
    if (t == SCAN_BS - 1) bsum[b] = s[t];
}

__global__ __launch_bounds__(256) void k_scan2(int* __restrict__ bsum, int nb) {
    __shared__ int s[256];
    int t = threadIdx.x;
    s[t] = (t < nb) ? bsum[t] : 0;
    __syncthreads();
    for (int off = 1; off < 256; off <<= 1) {
        int u = (t >= off) ? s[t - off] : 0;
        __syncthreads();
        s[t] += u;
        __syncthreads();
    }
    if (t < nb) bsum[t] = s[t];
}

__global__ __launch_bounds__(SCAN_BS) void k_scan3(int* __restrict__ ends,
                                                   const int* __restrict__ bsum, int n) {
    int t = threadIdx.x, b = blockIdx.x;
    int id = b * SCAN_BS + t;
    if (b > 0 && id < n) ends[id] += bsum[b - 1];
}

__global__ __launch_bounds__(256) void k_histpos(const int* __restrict__ dst,
                                                 int* __restrict__ cnt,
                                                 int* __restrict__ pos) {
    int e = blockIdx.x * 256 + threadIdx.x;
    if (e < N_EDGES) pos[e] = atomicAdd(&cnt[dst[e]], 1);
}

__global__ __launch_bounds__(256) void k_fill2(const int* __restrict__ src,
                                               const int* __restrict__ dst,
                                               const int* __restrict__ pos,
                                               const int* __restrict__ ends,
                                               int* __restrict__ csr) {
    int e = blockIdx.x * 256 + threadIdx.x;
    if (e >= N_EDGES) return;
    int d = dst[e];
    int start = (d > 0) ? ends[d - 1] : 0;
    csr[start + pos[e]] = src[e];
}

__global__ __launch_bounds__(256) void k_agg(const float* __restrict__ x,
                                             const int* __restrict__ csr,
                                             const int* __restrict__ ends,
                                             float* __restrict__ out) {
    int node = blockIdx.x * 4 + (threadIdx.x >> 6);
    if (node >= N_NODES) return;
    int f = threadIdx.x & 63;
    int start = (node > 0) ? ends[node - 1] : 0;
    int end = ends[node];
    float a0 = x[(size_t)node * D + f], a1 = 0.f, a2 = 0.f, a3 = 0.f;
    int e = start;
    for (; e + 4 <= end; e += 4) {
        int s0 = csr[e], s1 = csr[e + 1], s2 = csr[e + 2], s3 = csr[e + 3];
        a0 += x[(size_t)s0 * D + f];
        a1 += x[(size_t)s1 * D + f];
        a2 += x[(size_t)s2 * D + f];
        a3 += x[(size_t)s3 * D + f];
    }
    for (; e < end; e++) a0 += x[(size_t)csr[e] * D + f];
    out[(size_t)node * D + f] = (a0 + a1) + (a2 + a3);
}

// ===========================================================================
// Tier-C fallback: atomic scatter (R2-proven)
// ===========================================================================
__global__ __launch_bounds__(256) void k_init(const float4* __restrict__ x4,
                                              float4* __restrict__ agg4, int n4) {
    int i = blockIdx.x * 256 + threadIdx.x;
    if (i < n4) agg4[i] = x4[i];
}

__global__ __launch_bounds__(256) void k_scatter(const float4* __restrict__ x4,
                                                 const int* __restrict__ src,
                                                 const int* __restrict__ dst,
                                                 float* __restrict__ agg) {
    int gid = blockIdx.x * 256 + threadIdx.x;
    int e = gid >> 4;
    if (e >= N_EDGES) return;
    int c = gid & 15;
    float4 v = x4[src[e] * 16 + c];
    float* p = agg + (size_t)dst[e] * D + c * 4;
    atomicAdd(p + 0, v.x);
    atomicAdd(p + 1, v.y);
    atomicAdd(p + 2, v.z);
    atomicAdd(p + 3, v.w);
}

// ===========================================================================
// MFMA bf16 fused MLP, in-place on d_out (R6-proven).
// ===========================================================================
__global__ __launch_bounds__(256) void k_mlp_mfma(float* __restrict__ io,
                                                  const float* __restrict__ W1,
                                                  const float* __restrict__ b1,
                                                  const float* __restrict__ W2,
                                                  const float* __restrict__ b2) {
    __shared__ unsigned short sW1b[8192];
    __shared__ unsigned short sW2b[8192];
    __shared__ float sh[4][16 * SH_STRIDE];
    __shared__ float sb1[H];
    __shared__ float sb2[D];

    int t = threadIdx.x;

    for (int q = t; q < 8192; q += 256) {
        int j = q & 7, l = (q >> 3) & 63, f = q >> 9;
        int nt = f & 7, kt = f >> 3;
        int k = kt * 32 + ((l >> 4) << 3) + j;
        int n = nt * 16 + (l & 15);
        sW1b[q] = f2bf(W1[k * H + n]);
    }
    for (int q = t; q < 8192; q += 256) {
        int j = q & 7, l = (q >> 3) & 63, f = q >> 9;
        int nt = f & 3, kt = f >> 2;
        int k = kt * 32 + ((l >> 4) << 3) + j;
        int n = nt * 16 + (l & 15);
        sW2b[q] = f2bf(W2[k * D + n]);
    }
    if (t < H) sb1[t] = b1[t];
    if (t >= H && t < H + D) sb2[t - H] = b2[t - H];
    __syncthreads();

    int w = t >> 6, l = t & 63;
    int m = l & 15, q4 = l >> 4;
    float* shw = sh[w];

    const int NT16 = N_NODES / 16;
    const int WAVES = MFMA_GRID * 4;
    const int ITERS = (NT16 + WAVES - 1) / WAVES;

    for (int it = 0; it < ITERS; ++it) {
        int tl = it * WAVES + blockIdx.x * 4 + w;
        bool valid = tl < NT16;
        int nbase = tl * 16;

        if (valid) {
            const float* xr = io + (size_t)(nbase + m) * D + q4 * 8;
            float4 a0 = *(const float4*)(xr);
            float4 a1 = *(const float4*)(xr + 4);
            float4 c0 = *(const float4*)(xr + 32);
            float4 c1 = *(const float4*)(xr + 36);
            short8 A0, A1;
            A0[0] = f2bf(a0.x); A0[1] = f2bf(a0.y); A0[2] = f2bf(a0.z); A0[3] = f2bf(a0.w);
            A0[4] = f2bf(a1.x); A0[5] = f2bf(a1.y); A0[6] = f2bf(a1.z); A0[7] = f2bf(a1.w);
            A1[0] = f2bf(c0.x); A1[1] = f2bf(c0.y); A1[2] = f2bf(c0.z); A1[3] = f2bf(c0.w);
            A1[4] = f2bf(c1.x); A1[5] = f2bf(c1.y); A1[6] = f2bf(c1.z); A1[7] = f2bf(c1.w);

#pragma unroll
            for (int nt = 0; nt < 8; nt++) {
                float bv = sb1[nt * 16 + m];
                floatx4 acc = {bv, bv, bv, bv};
                short8 B0 = *(const short8*)&sW1b[(0 * 8 + nt) * 512 + l * 8];
                short8 B1 = *(const short8*)&sW1b[(1 * 8 + nt) * 512 + l * 8];
                acc = __builtin_amdgcn_mfma_f32_16x16x32_bf16(A0, B0, acc, 0, 0, 0);
                acc = __builtin_amdgcn_mfma_f32_16x16x32_bf16(A1, B1, acc, 0, 0, 0);
#pragma unroll
                for (int r = 0; r < 4; r++)
                    shw[(q4 * 4 + r) * SH_STRIDE + nt * 16 + m] = fmaxf(acc[r], 0.f);
            }
        }
        __syncthreads();

        if (valid) {
            short8 Ah[4];
#pragma unroll
            for (int kt = 0; kt < 4; kt++) {
                const float* hr = &shw[m * SH_STRIDE + kt * 32 + q4 * 8];
                float4 h0 = *(const float4*)(hr);
                float4 h1 = *(const float4*)(hr + 4);
                Ah[kt][0] = f2bf(h0.x); Ah[kt][1] = f2bf(h0.y);
                Ah[kt][2] = f2bf(h0.z); Ah[kt][3] = f2bf(h0.w);
                Ah[kt][4] = f2bf(h1.x); Ah[kt][5] = f2bf(h1.y);
                Ah[kt][6] = f2bf(h1.z); Ah[kt][7] = f2bf(h1.w);
            }
#pragma unroll
            for (int nt = 0; nt < 4; nt++) {
                float bv = sb2[nt * 16 + m];
                floatx4 acc = {bv, bv, bv, bv};
#pragma unroll
                for (int kt = 0; kt < 4; kt++) {
                    short8 B = *(const short8*)&sW2b[(kt * 4 + nt) * 512 + l * 8];
                    acc = __builtin_amdgcn_mfma_f32_16x16x32_bf16(Ah[kt], B, acc, 0, 0, 0);
                }
#pragma unroll
                for (int r = 0; r < 4; r++)
                    io[(size_t)(nbase + q4 * 4 + r) * D + nt * 16 + m] = acc[r];
            }
        }
        __syncthreads();
    }
}

// ===========================================================================
extern "C" void kernel_launch(void* const* d_in, const int* in_sizes, int n_in,
                              void* d_out, int out_size, void* d_ws, size_t ws_size,
                              hipStream_t stream) {
    const float* x  = (const float*)d_in[0];
    const int* eidx = (const int*)d_in[1];   // [2, N_EDGES] int32 per harness
    const float* W1 = (const float*)d_in[2];
    const float* b1 = (const float*)d_in[3];
    const float* W2 = (const float*)d_in[4];
    const float* b2 = (const float*)d_in[5];
    float* out      = (float*)d_out;

    const int* src = eidx;
    const int* dst = eidx + N_EDGES;

    int ge = (N_EDGES + 255) / 256;
    int n4 = N_NODES * D / 4;

    // Tier A: x16[N*D bf16] ebuf[E] M2[NCHUNK*NB] colsum[NB] bends[NB]
    //         ovfn[4] ovf[2*OVF_CAP]                        ~= 20.9 MB
    size_t need_A = (size_t)N_NODES * D * sizeof(unsigned short)
                  + (size_t)(N_EDGES + NCHUNK * NB + 2 * NB + 4 + 2 * OVF_CAP) * sizeof(int);
    // Tier B: cnt[N] ends[N] bsum[512] pos[E] csr[E] (~13.6 MB)
    size_t need_B = (size_t)(2 * N_NODES + 512 + 2 * N_EDGES) * sizeof(int);

    if (ws_size >= need_A) {
        unsigned short* x16 = (unsigned short*)d_ws;
        int* ebuf   = (int*)(x16 + (size_t)N_NODES * D);
        int* M2     = ebuf + N_EDGES;
        int* colsum = M2 + NCHUNK * NB;
        int* bends  = colsum + NB;
        int* ovfn   = bends + NB;
        int* ovf    = ovfn + 4;

        k_xbf16<<<(n4 + 255) / 256, 256, 0, stream>>>((const float4*)x, (ushort4_t*)x16, n4);
        k_bhist<<<NCHUNK, 256, 0, stream>>>(dst, M2, ovfn);
        k_colscan<<<(NB + 255) / 256, 256, 0, stream>>>(M2, colsum);
        k_bscan<<<1, 512, 0, stream>>>(colsum, bends);
        k_part<<<NCHUNK, 256, 0, stream>>>(src, dst, M2, bends, ebuf);
        k_bagg3<<<NB, 256, 0, stream>>>(x, x16, ebuf, bends, ovfn, ovf, out);
        k_ovf<<<1, 256, 0, stream>>>(ovfn, ovf, x, out);
    } else if (ws_size >= need_B) {
        int* cnt  = (int*)d_ws;
        int* ends = cnt + N_NODES;
        int* bsum = ends + N_NODES;
        int* pos  = bsum + 512;
        int* csr  = pos + N_EDGES;

        k_zero<<<(N_NODES + 255) / 256, 256, 0, stream>>>(cnt, N_NODES);
        k_histpos<<<ge, 256, 0, stream>>>(dst, cnt, pos);
        k_scan1<<<SCAN_NBLK, SCAN_BS, 0, stream>>>(cnt, ends, bsum, N_NODES);
        k_scan2<<<1, 256, 0, stream>>>(bsum, SCAN_NBLK);
        k_scan3<<<SCAN_NBLK, SCAN_BS, 0, stream>>>(ends, bsum, N_NODES);
        k_fill2<<<ge, 256, 0, stream>>>(src, dst, pos, ends, csr);
        k_agg<<<(N_NODES + 3) / 4, 256, 0, stream>>>(x, csr, ends, out);
    } else {
        k_init<<<(n4 + 255) / 256, 256, 0, stream>>>((const float4*)x, (float4*)out, n4);
        long long total = (long long)N_EDGES * 16;
        k_scatter<<<(int)((total + 255) / 256), 256, 0, stream>>>(
            (const float4*)x, src, dst, out);
    }

    k_mlp_mfma<<<MFMA_GRID, 256, 0, stream>>>(out, W1, b1, W2, b2);
}